// Round 2
// baseline (73.100 us; speedup 1.0000x reference)
//
#include <hip/hip_runtime.h>
#include <hip/hip_bf16.h>

// Reference returns x unchanged (attention path is dead code). Output = x:
// [8,64,4096] float32 = 2,097,152 elements = 8 MiB.
//
// Round-1 lesson: hipMemcpyAsync D2D under graph capture went to an SDMA
// engine (~241 GB/s -> 69.5 us). A compute-blit float4 copy kernel uses the
// full VALU/L2 path (~6.3 TB/s) instead.

__global__ __launch_bounds__(256) void copy_f4(const float4* __restrict__ src,
                                               float4* __restrict__ dst,
                                               int n4) {
    int i = blockIdx.x * blockDim.x + threadIdx.x;
    if (i < n4) dst[i] = src[i];
}

extern "C" void kernel_launch(void* const* d_in, const int* in_sizes, int n_in,
                              void* d_out, int out_size, void* d_ws, size_t ws_size,
                              hipStream_t stream) {
    const float4* x = (const float4*)d_in[0];
    float4* out = (float4*)d_out;
    int n4 = out_size / 4;  // 2,097,152 / 4 = 524,288 float4s
    int block = 256;
    int grid = (n4 + block - 1) / block;  // 2048 blocks
    copy_f4<<<grid, block, 0, stream>>>(x, out, n4);
}

// Round 3
// 71.835 us; speedup vs baseline: 1.0176x; 1.0176x over previous
//
#include <hip/hip_runtime.h>
#include <hip/hip_bf16.h>

// Reference returns x unchanged (the attention path is dead code, faithful to
// the original torch module). Output = input x: [8,64,4096] float32 = 8 MiB.
//
// Round-2 lesson: dur_us (~70 us) is dominated by fixed harness work
// (268 MB d_ws re-poison fills at ~41 us + input restores), not by our copy.
// SDMA memcpy (69.5 us) measured slightly faster than a compute blit
// (73.1 us) — the copy-engine op overlaps with the harness's compute-queue
// fills. Revert to the memcpy variant.

extern "C" void kernel_launch(void* const* d_in, const int* in_sizes, int n_in,
                              void* d_out, int out_size, void* d_ws, size_t ws_size,
                              hipStream_t stream) {
    const float* x = (const float*)d_in[0];
    float* out = (float*)d_out;
    const size_t nbytes = (size_t)out_size * sizeof(float);  // 8 MiB
    hipMemcpyAsync(out, x, nbytes, hipMemcpyDeviceToDevice, stream);
}